// Round 18
// baseline (124.459 us; speedup 1.0000x reference)
//
#include <hip/hip_runtime.h>
#include <stdint.h>

typedef float f32x4 __attribute__((ext_vector_type(4)));
typedef float f32x16 __attribute__((ext_vector_type(16)));
typedef __bf16 bf16x8 __attribute__((ext_vector_type(8)));
typedef unsigned int u32x4 __attribute__((ext_vector_type(4)));
typedef unsigned short u16x4 __attribute__((ext_vector_type(4)));

#define DEV __device__ __forceinline__

// SCALE * log2(e): softmax computed base-2 (exact-equivalent)
#define QSCALE_LOG2E 0.18033688011112042f

// round-to-nearest-even f32 -> bf16 bits
DEV unsigned short f2bf(float f) {
    unsigned u = __builtin_bit_cast(unsigned, f);
    u += 0x7fffu + ((u >> 16) & 1u);
    return (unsigned short)(u >> 16);
}

// native cast path: compiler emits v_cvt_pk_bf16_f32 for pairs (RNE)
DEV unsigned pack2bf(float a, float b) {
    unsigned short ua = __builtin_bit_cast(unsigned short, (__bf16)a);
    unsigned short ub = __builtin_bit_cast(unsigned short, (__bf16)b);
    return (unsigned)ua | ((unsigned)ub << 16);
}

// lane i <-> lane i^32 pairwise exchange of two registers (gfx950)
DEV void pswap(unsigned& a, unsigned& b) {
    asm volatile("v_permlane32_swap_b32 %0, %1" : "+v"(a), "+v"(b));
}

// async global->LDS, 16B per lane. LDS dst must be wave-uniform-base + lane*16.
DEV void gload16(const void* g, void* l) {
    __builtin_amdgcn_global_load_lds(
        (const __attribute__((address_space(1))) unsigned int*)(uintptr_t)g,
        (__attribute__((address_space(3))) unsigned int*)(unsigned int)(uintptr_t)l,
        16, 0, 0);
}

// ---------------- fp32 -> bf16 elementwise ----------------
__global__ void k_cvt(const float* __restrict__ in, unsigned short* __restrict__ out, int n4) {
    int i = blockIdx.x * 256 + threadIdx.x;
    int st = gridDim.x * 256;
    for (; i < n4; i += st) {
        f32x4 v = *(const f32x4*)(in + (size_t)i * 4);
        u16x4 o;
        o[0] = f2bf(v[0]); o[1] = f2bf(v[1]); o[2] = f2bf(v[2]); o[3] = f2bf(v[3]);
        *(u16x4*)(out + (size_t)i * 4) = o;
    }
}

// ---------------- fp32 [1024][Nc] -> bf16 [Nc][1024] transpose ----------------
__global__ void k_transpose(const float* __restrict__ in, unsigned short* __restrict__ out, int Nc) {
    __shared__ unsigned short tl[64][68];
    int n0 = blockIdx.x * 64, k0 = blockIdx.y * 64;
#pragma unroll
    for (int i = 0; i < 16; i++) {
        int idx = i * 256 + threadIdx.x;
        int kr = idx >> 6, nc = idx & 63;
        tl[kr][nc] = f2bf(in[(size_t)(k0 + kr) * Nc + n0 + nc]);
    }
    __syncthreads();
#pragma unroll
    for (int i = 0; i < 8; i++) {
        int idx = i * 256 + threadIdx.x;
        int nr = idx >> 5, kp2 = idx & 31;
        unsigned vv = (unsigned)tl[kp2 * 2][nr] | ((unsigned)tl[kp2 * 2 + 1][nr] << 16);
        *(unsigned*)(out + (size_t)(n0 + nr) * 1024 + k0 + kp2 * 2) = vv;
    }
}

// ---------------- GEMM1: 256x256 tile, BK=64, 8 waves, 4-phase K-loop --------
// (unchanged from round 16)
__global__ __launch_bounds__(512, 2) void k_gemm1_256(
    const unsigned short* __restrict__ A, const unsigned short* __restrict__ Bt, int K,
    unsigned short* __restrict__ q, unsigned short* __restrict__ kk_,
    unsigned short* __restrict__ vT) {
    __shared__ unsigned short Ab[2][256 * 64];   // 32KB each
    __shared__ unsigned short Bb[2][256 * 64];
    const int tid = threadIdx.x;
    const int w = tid >> 6, l = tid & 63, g = l >> 4, lr = l & 15;
    const int wm = w >> 2, wn = w & 3;
    const int nwg = gridDim.x * gridDim.y, cpx = nwg >> 3;
    const int lin = blockIdx.y * gridDim.x + blockIdx.x;
    const int swz = (lin & 7) * cpx + (lin >> 3);
    const int m0 = (swz / gridDim.x) * 256, n0 = (swz % gridDim.x) * 256;
    f32x4 acc[8][4] = {};

    auto SPART = [&](int db, int kt, int i) {
        int ci = i * 512 + tid;
        int row = ci >> 3, pos = ci & 7;
        int gc = (pos ^ (row & 7)) * 8;
        gload16(A + (size_t)(m0 + row) * K + kt * 64 + gc, (char*)Ab[db] + ci * 16);
        gload16(Bt + (size_t)(n0 + row) * K + kt * 64 + gc, (char*)Bb[db] + ci * 16);
    };

#pragma unroll
    for (int i = 0; i < 4; i++) SPART(0, 0, i);
    asm volatile("s_waitcnt vmcnt(0)" ::: "memory");
    __builtin_amdgcn_s_barrier();
    __builtin_amdgcn_sched_barrier(0);

    const int nt = K >> 6;   // 16
    for (int t = 0; t < nt; ++t) {
        const int db = t & 1;
        const char* Ac = (const char*)Ab[db];
        const char* Bc = (const char*)Bb[db];
        bf16x8 bfv[4][2];
#pragma unroll
        for (int qp = 0; qp < 4; qp++) {
            if (qp == 0) {
#pragma unroll
                for (int ni = 0; ni < 4; ni++)
#pragma unroll
                    for (int kk = 0; kk < 2; kk++) {
                        int row = wn * 64 + ni * 16 + lr;
                        int c = kk * 4 + g;
                        bfv[ni][kk] = *(const bf16x8*)(Bc + row * 128 + ((c ^ (row & 7)) * 16));
                    }
            }
            bf16x8 af[2][2];
#pragma unroll
            for (int j = 0; j < 2; j++)
#pragma unroll
                for (int kk = 0; kk < 2; kk++) {
                    int row = wm * 128 + (2 * qp + j) * 16 + lr;
                    int c = kk * 4 + g;
                    af[j][kk] = *(const bf16x8*)(Ac + row * 128 + ((c ^ (row & 7)) * 16));
                }
            if (t < nt - 1 && qp < 2) {
                SPART(db ^ 1, t + 1, 2 * qp);
                SPART(db ^ 1, t + 1, 2 * qp + 1);
            }
            __builtin_amdgcn_s_barrier();
            asm volatile("s_waitcnt lgkmcnt(0)" ::: "memory");
            __builtin_amdgcn_sched_barrier(0);   // rule #18
            __builtin_amdgcn_s_setprio(1);
#pragma unroll
            for (int kk = 0; kk < 2; kk++)
#pragma unroll
                for (int j = 0; j < 2; j++)
#pragma unroll
                    for (int ni = 0; ni < 4; ni++)
                        acc[2 * qp + j][ni] = __builtin_amdgcn_mfma_f32_16x16x32_bf16(
                            af[j][kk], bfv[ni][kk], acc[2 * qp + j][ni], 0, 0, 0);
            __builtin_amdgcn_s_setprio(0);
            if (qp == 3 && t < nt - 1)
                asm volatile("s_waitcnt vmcnt(0)" ::: "memory");
            __builtin_amdgcn_s_barrier();
            __builtin_amdgcn_sched_barrier(0);
        }
    }

#pragma unroll
    for (int mi = 0; mi < 8; mi++) {
#pragma unroll
        for (int ni = 0; ni < 4; ni++) {
            int row0 = m0 + wm * 128 + mi * 16 + g * 4;
            int col = n0 + wn * 64 + ni * 16 + lr;
            int b = row0 >> 11, nn = row0 & 2047;
            int which = col >> 10, cc = col & 1023;
            int h = cc >> 6, d = cc & 63;
            if (which == 2) {
                u16x4 pv;
#pragma unroll
                for (int r = 0; r < 4; r++) pv[r] = f2bf(acc[mi][ni][r]);
                *(u16x4*)&vT[((size_t)(b * 16 + h) * 64 + d) * 2048 + nn] = pv;
            } else {
                unsigned short* dst = (which == 0) ? q : kk_;
                const float sc = (which == 0) ? QSCALE_LOG2E : 1.f;
#pragma unroll
                for (int r = 0; r < 4; r++)
                    dst[((size_t)(b * 16 + h) * 2048 + nn + r) * 64 + d] = f2bf(acc[mi][ni][r] * sc);
            }
        }
    }
}

// ---------------- GEMM (128x128, R12 dbuf): out-proj (MODE 3) ----------------
__global__ __launch_bounds__(256) void k_gemm3(
    const unsigned short* __restrict__ A, const unsigned short* __restrict__ Bt, int K,
    const float* __restrict__ bias, float* __restrict__ outf) {
    __shared__ unsigned short As[2][128 * 64];
    __shared__ unsigned short Bs[2][128 * 64];
    const int tid = threadIdx.x;
    const int w = tid >> 6, l = tid & 63, g = l >> 4, lr = l & 15;
    const int wr = w >> 1, wc = w & 1;
    const int nwg = gridDim.x * gridDim.y, cpx = nwg >> 3;
    const int lin = blockIdx.y * gridDim.x + blockIdx.x;
    const int swz = (lin & 7) * cpx + (lin >> 3);
    const int m0 = (swz / gridDim.x) * 128, n0 = (swz % gridDim.x) * 128;
    f32x4 acc[4][4] = {};

    auto STAGE = [&](int buf, int k0) {
#pragma unroll
        for (int i = 0; i < 4; i++) {
            int c = i * 256 + tid;
            gload16(A + (size_t)(m0 + (c >> 3)) * K + k0 + (c & 7) * 8, (char*)As[buf] + c * 16);
            gload16(Bt + (size_t)(n0 + (c >> 3)) * K + k0 + (c & 7) * 8, (char*)Bs[buf] + c * 16);
        }
    };

    STAGE(0, 0);
    asm volatile("s_waitcnt vmcnt(0)" ::: "memory");
    __builtin_amdgcn_s_barrier();
    __builtin_amdgcn_sched_barrier(0);

    int cur = 0;
    for (int k0 = 0; k0 < K; k0 += 64) {
        if (k0 + 64 < K) STAGE(cur ^ 1, k0 + 64);
        const unsigned short* Ac = As[cur];
        const unsigned short* Bc = Bs[cur];
#pragma unroll
        for (int kk = 0; kk < 2; kk++) {
            bf16x8 af[4], bfv[4];
#pragma unroll
            for (int mi = 0; mi < 4; mi++)
                af[mi] = *(const bf16x8*)(Ac + (wr * 64 + mi * 16 + lr) * 64 + kk * 32 + g * 8);
#pragma unroll
            for (int ni = 0; ni < 4; ni++)
                bfv[ni] = *(const bf16x8*)(Bc + (wc * 64 + ni * 16 + lr) * 64 + kk * 32 + g * 8);
#pragma unroll
            for (int mi = 0; mi < 4; mi++)
#pragma unroll
                for (int ni = 0; ni < 4; ni++)
                    acc[mi][ni] = __builtin_amdgcn_mfma_f32_16x16x32_bf16(af[mi], bfv[ni], acc[mi][ni], 0, 0, 0);
        }
        asm volatile("s_waitcnt vmcnt(0)" ::: "memory");
        __builtin_amdgcn_s_barrier();
        __builtin_amdgcn_sched_barrier(0);
        cur ^= 1;
    }

#pragma unroll
    for (int mi = 0; mi < 4; mi++)
#pragma unroll
        for (int ni = 0; ni < 4; ni++)
#pragma unroll
            for (int r = 0; r < 4; r++) {
                int row = m0 + wr * 64 + mi * 16 + g * 4 + r;
                int col = n0 + wc * 64 + ni * 16 + lr;
                outf[(size_t)row * 1024 + col] = acc[mi][ni][r] + bias[col];
            }
}

// ---------------- flash attention: wave-private buffers, FREE-RUNNING --------
// Round 18: R12-R17 established attn time is proportional to total work per
// SIMD while NO pipe exceeds ~15% utilization -- dependency-chain-bound with
// block-barrier lockstep preventing cross-wave phase overlap. Fix: each wave
// owns a PRIVATE 16KB LDS buffer (K 8KB + V 8KB, KV-64, dual-q W=64) -> NO
// barrier in the loop. T14 split staging per operand: load K(t+1) at top,
// write after QK; load V(t+1) before softmax (flight = SM+PV), write at
// bottom. 2 blocks/CU -> 2 free-running waves/SIMD from different blocks:
// one wave's softmax VALU overlaps the other's MFMA (m114). R8's failure
// causes (8x line-amp gather, zero flight) are both absent here.
__global__ __launch_bounds__(256, 2) void k_attn(
    const unsigned short* __restrict__ qb, const unsigned short* __restrict__ kb,
    const unsigned short* __restrict__ vTb, unsigned short* __restrict__ ao) {
    __shared__ __align__(16) char smem[65536];   // 4 waves x private 16KB
    const int tid = threadIdx.x;
    const int w = tid >> 6, l = tid & 63, l31 = l & 31, hf = l >> 5;
    const int qg = w >> 1, kvh = w & 1;
    // XCD-grouped decode: 512 blocks = 8 xcd x (4 bh x 16 qb)
    const int bid = blockIdx.x;
    const int xcd = bid & 7, slot = bid >> 3;
    const int bh = xcd * 4 + (slot >> 4), qb_ = slot & 15;
    const int b = bh >> 4, h = bh & 15;
    const unsigned short* qp = qb + (size_t)bh * 131072;
    const unsigned short* kp = kb + (size_t)bh * 131072 + (size_t)kvh * 65536;
    const unsigned short* vTp = vTb + (size_t)bh * 131072 + kvh * 1024;

    // dual q-tile: qrow_t = qb_*128 + qg*64 + ti*32 + l31
    const int qrow0 = qb_ * 128 + qg * 64 + l31;
    bf16x8 qf[2][4];
#pragma unroll
    for (int ti = 0; ti < 2; ti++)
#pragma unroll
        for (int dc = 0; dc < 4; dc++)
            qf[ti][dc] = *(const bf16x8*)(qp + (size_t)(qrow0 + ti * 32) * 64 + dc * 16 + hf * 8);

    f32x16 o_acc[2][2] = {};
    float l_r[2] = {0.f, 0.f};

    // wave-private buffer: K at +0 (8KB), V at +8192
    char* p0 = smem + w * 16384;
    const int sr8 = l >> 3;
    const int sco = ((l & 7) ^ sr8) * 8;     // inverse-swizzled source chunk

    u32x4 sreg[8];
    auto LOADK = [&](int kv0) {
#pragma unroll
        for (int r = 0; r < 8; r++)
            sreg[r] = *(const u32x4*)(kp + (size_t)(kv0 + r * 8 + sr8) * 64 + sco);
    };
    auto LOADV = [&](int kv0) {
#pragma unroll
        for (int r = 0; r < 8; r++)
            sreg[r] = *(const u32x4*)(vTp + (size_t)(r * 8 + sr8) * 2048 + kv0 + sco);
    };
    auto WRITEB = [&](int off) {
#pragma unroll
        for (int r = 0; r < 8; r++)
            *(u32x4*)(p0 + off + r * 1024 + (size_t)l * 16) = sreg[r];
    };

    // ---- prologue: tile 0 staged (K then V through the same regs) ----
    LOADK(0);
    asm volatile("s_waitcnt vmcnt(0)" ::: "memory");
    WRITEB(0);
    LOADV(0);
    asm volatile("s_waitcnt vmcnt(0)" ::: "memory");
    WRITEB(8192);
    asm volatile("s_waitcnt lgkmcnt(0)" ::: "memory");
    __builtin_amdgcn_sched_barrier(0);

    const int lb = l31 & 7;
    for (int t = 0; t < 16; ++t) {
        const int kvn = (t + 1) * 64;
        // ---- issue K(t+1) loads (flight = QK phase) ----
        if (t < 15) LOADK(kvn);
        __builtin_amdgcn_sched_barrier(0);

        // ---- S^T = K x Q ----
        f32x16 s[2][2] = {};
        __builtin_amdgcn_s_setprio(1);
#pragma unroll
        for (int kt = 0; kt < 2; kt++)
#pragma unroll
            for (int dc = 0; dc < 4; dc++) {
                bf16x8 kf = *(const bf16x8*)(p0 + (kt * 32 + l31) * 128 + (((2 * dc + hf) ^ lb) * 16));
                s[0][kt] = __builtin_amdgcn_mfma_f32_32x32x16_bf16(kf, qf[0][dc], s[0][kt], 0, 0, 0);
                s[1][kt] = __builtin_amdgcn_mfma_f32_32x32x16_bf16(kf, qf[1][dc], s[1][kt], 0, 0, 0);
            }
        __builtin_amdgcn_s_setprio(0);

        // ---- K reads drained + K(t+1) arrived -> overwrite K region ----
        if (t < 15) {
            asm volatile("s_waitcnt lgkmcnt(0)" ::: "memory");
            asm volatile("s_waitcnt vmcnt(0)" ::: "memory");
            __builtin_amdgcn_sched_barrier(0);
            WRITEB(0);
            // ---- issue V(t+1) loads (flight = softmax + PV) ----
            LOADV(kvn);
            __builtin_amdgcn_sched_barrier(0);
        }

        // ---- softmax numerator per tile: P = exp2(s), no max subtraction ----
        bf16x8 pf[2][4];
#pragma unroll
        for (int ti = 0; ti < 2; ti++) {
            float s0 = 0.f, s1 = 0.f, s2 = 0.f, s3 = 0.f;
#pragma unroll
            for (int kt = 0; kt < 2; kt++)
#pragma unroll
                for (int r = 0; r < 16; r += 4) {
                    float e0 = __builtin_amdgcn_exp2f(s[ti][kt][r]);
                    float e1 = __builtin_amdgcn_exp2f(s[ti][kt][r + 1]);
                    float e2 = __builtin_amdgcn_exp2f(s[ti][kt][r + 2]);
                    float e3 = __builtin_amdgcn_exp2f(s[ti][kt][r + 3]);
                    s[ti][kt][r] = e0; s[ti][kt][r + 1] = e1;
                    s[ti][kt][r + 2] = e2; s[ti][kt][r + 3] = e3;
                    s0 += e0; s1 += e1; s2 += e2; s3 += e3;
                }
            float ssum = (s0 + s1) + (s2 + s3);
            ssum += __shfl_xor(ssum, 32);
            l_r[ti] += ssum;
#pragma unroll
            for (int kt = 0; kt < 2; kt++) {
                unsigned wd[8];
#pragma unroll
                for (int i = 0; i < 8; i++)
                    wd[i] = pack2bf(s[ti][kt][2 * i], s[ti][kt][2 * i + 1]);
#pragma unroll
                for (int cl = 0; cl < 2; cl++) {
                    unsigned b0 = wd[4 * cl + 0], b2 = wd[4 * cl + 2];
                    unsigned b1 = wd[4 * cl + 1], b3 = wd[4 * cl + 3];
                    pswap(b0, b2);
                    pswap(b1, b3);
                    u32x4 bw; bw[0] = b0; bw[1] = b1; bw[2] = b2; bw[3] = b3;
                    pf[ti][2 * kt + cl] = __builtin_bit_cast(bf16x8, bw);
                }
            }
        }

        // ---- O^T += V^T x P ----
        __builtin_amdgcn_s_setprio(1);
#pragma unroll
        for (int c4 = 0; c4 < 4; c4++)
#pragma unroll
            for (int dt = 0; dt < 2; dt++) {
                bf16x8 vf = *(const bf16x8*)(p0 + 8192 + (dt * 32 + l31) * 128 + (((2 * c4 + hf) ^ lb) * 16));
                o_acc[0][dt] = __builtin_amdgcn_mfma_f32_32x32x16_bf16(vf, pf[0][c4], o_acc[0][dt], 0, 0, 0);
                o_acc[1][dt] = __builtin_amdgcn_mfma_f32_32x32x16_bf16(vf, pf[1][c4], o_acc[1][dt], 0, 0, 0);
            }
        __builtin_amdgcn_s_setprio(0);

        // ---- V reads drained + V(t+1) arrived -> overwrite V region ----
        if (t < 15) {
            asm volatile("s_waitcnt lgkmcnt(0)" ::: "memory");
            asm volatile("s_waitcnt vmcnt(0)" ::: "memory");
            __builtin_amdgcn_sched_barrier(0);
            WRITEB(8192);
            asm volatile("s_waitcnt lgkmcnt(0)" ::: "memory");
            __builtin_amdgcn_sched_barrier(0);
        }
    }

    // ---- merge the two KV halves, two passes (one per q-tile) ----
    float* dO = (float*)(smem + qg * 8448);            // [64 lane][33] padded
    float* dL = (float*)(smem + 16896 + qg * 256);
#pragma unroll
    for (int ti = 0; ti < 2; ti++) {
        __syncthreads();
        if (kvh == 1) {
#pragma unroll
            for (int i = 0; i < 16; i++) dO[l * 33 + i] = o_acc[ti][0][i];
#pragma unroll
            for (int i = 0; i < 16; i++) dO[l * 33 + 16 + i] = o_acc[ti][1][i];
            dL[l] = l_r[ti];
        }
        __syncthreads();
        if (kvh == 0) {
            float linv = 1.f / (l_r[ti] + dL[l]);
            unsigned short* aop = ao + ((size_t)b * 2048 + qrow0 + ti * 32) * 1024 + h * 64;
#pragma unroll
            for (int dt = 0; dt < 2; dt++)
#pragma unroll
                for (int rg = 0; rg < 4; rg++) {
                    u16x4 pv;
#pragma unroll
                    for (int k = 0; k < 4; k++) {
                        int r = rg * 4 + k;
                        pv[k] = f2bf((o_acc[ti][dt][r] + dO[l * 33 + dt * 16 + r]) * linv);
                    }
                    *(u16x4*)(aop + 8 * rg + 4 * hf + 32 * dt) = pv;
                }
        }
    }
}

extern "C" void kernel_launch(void* const* d_in, const int* in_sizes, int n_in,
                              void* d_out, int out_size, void* d_ws, size_t ws_size,
                              hipStream_t stream) {
    (void)in_sizes; (void)n_in; (void)out_size; (void)ws_size;
    const float* x      = (const float*)d_in[0];
    const float* w_qkv  = (const float*)d_in[1];
    const float* w_proj = (const float*)d_in[2];
    const float* b_proj = (const float*)d_in[3];
    float* out = (float*)d_out;
    char* ws = (char*)d_ws;

    // workspace layout (bytes); ao aliases xb (xb dead after GEMM1)
    unsigned short* xb     = (unsigned short*)(ws);             // [4096][1024] bf16
    unsigned short* ao     = (unsigned short*)(ws);             // [4096][1024] bf16 (alias)
    unsigned short* wqkvT  = (unsigned short*)(ws + 8388608);   // [3072][1024] bf16
    unsigned short* wprojT = (unsigned short*)(ws + 14680064);  // [1024][1024] bf16
    unsigned short* qb     = (unsigned short*)(ws + 16777216);  // [2][16][2048][64] bf16
    unsigned short* kb     = (unsigned short*)(ws + 25165824);  // [2][16][2048][64] bf16
    unsigned short* vTb    = (unsigned short*)(ws + 33554432);  // [2][16][64][2048] bf16

    k_cvt<<<2048, 256, 0, stream>>>(x, xb, 1048576);
    k_transpose<<<dim3(48, 16), 256, 0, stream>>>(w_qkv, wqkvT, 3072);
    k_transpose<<<dim3(16, 16), 256, 0, stream>>>(w_proj, wprojT, 1024);
    k_gemm1_256<<<dim3(12, 16), 512, 0, stream>>>(xb, wqkvT, 1024, qb, kb, vTb);
    k_attn<<<512, 256, 0, stream>>>(qb, kb, vTb, ao);
    k_gemm3<<<dim3(8, 32), 256, 0, stream>>>(ao, wprojT, 1024, b_proj, out);
}

// Round 19
// 116.789 us; speedup vs baseline: 1.0657x; 1.0657x over previous
//
#include <hip/hip_runtime.h>
#include <stdint.h>

typedef float f32x4 __attribute__((ext_vector_type(4)));
typedef float f32x16 __attribute__((ext_vector_type(16)));
typedef __bf16 bf16x8 __attribute__((ext_vector_type(8)));
typedef unsigned int u32x4 __attribute__((ext_vector_type(4)));
typedef unsigned short u16x4 __attribute__((ext_vector_type(4)));

#define DEV __device__ __forceinline__

// SCALE * log2(e): softmax computed base-2 (exact-equivalent)
#define QSCALE_LOG2E 0.18033688011112042f

// round-to-nearest-even f32 -> bf16 bits
DEV unsigned short f2bf(float f) {
    unsigned u = __builtin_bit_cast(unsigned, f);
    u += 0x7fffu + ((u >> 16) & 1u);
    return (unsigned short)(u >> 16);
}

// native cast path: compiler emits v_cvt_pk_bf16_f32 for pairs (RNE)
DEV unsigned pack2bf(float a, float b) {
    unsigned short ua = __builtin_bit_cast(unsigned short, (__bf16)a);
    unsigned short ub = __builtin_bit_cast(unsigned short, (__bf16)b);
    return (unsigned)ua | ((unsigned)ub << 16);
}

// lane i <-> lane i^32 pairwise exchange of two registers (gfx950)
DEV void pswap(unsigned& a, unsigned& b) {
    asm volatile("v_permlane32_swap_b32 %0, %1" : "+v"(a), "+v"(b));
}

// async global->LDS, 16B per lane. LDS dst must be wave-uniform-base + lane*16.
DEV void gload16(const void* g, void* l) {
    __builtin_amdgcn_global_load_lds(
        (const __attribute__((address_space(1))) unsigned int*)(uintptr_t)g,
        (__attribute__((address_space(3))) unsigned int*)(unsigned int)(uintptr_t)l,
        16, 0, 0);
}

// ---------------- fp32 -> bf16 elementwise ----------------
__global__ void k_cvt(const float* __restrict__ in, unsigned short* __restrict__ out, int n4) {
    int i = blockIdx.x * 256 + threadIdx.x;
    int st = gridDim.x * 256;
    for (; i < n4; i += st) {
        f32x4 v = *(const f32x4*)(in + (size_t)i * 4);
        u16x4 o;
        o[0] = f2bf(v[0]); o[1] = f2bf(v[1]); o[2] = f2bf(v[2]); o[3] = f2bf(v[3]);
        *(u16x4*)(out + (size_t)i * 4) = o;
    }
}

// ---------------- fp32 [1024][Nc] -> bf16 [Nc][1024] transpose ----------------
__global__ void k_transpose(const float* __restrict__ in, unsigned short* __restrict__ out, int Nc) {
    __shared__ unsigned short tl[64][68];
    int n0 = blockIdx.x * 64, k0 = blockIdx.y * 64;
#pragma unroll
    for (int i = 0; i < 16; i++) {
        int idx = i * 256 + threadIdx.x;
        int kr = idx >> 6, nc = idx & 63;
        tl[kr][nc] = f2bf(in[(size_t)(k0 + kr) * Nc + n0 + nc]);
    }
    __syncthreads();
#pragma unroll
    for (int i = 0; i < 8; i++) {
        int idx = i * 256 + threadIdx.x;
        int nr = idx >> 5, kp2 = idx & 31;
        unsigned vv = (unsigned)tl[kp2 * 2][nr] | ((unsigned)tl[kp2 * 2 + 1][nr] << 16);
        *(unsigned*)(out + (size_t)(n0 + nr) * 1024 + k0 + kp2 * 2) = vv;
    }
}

// ---------------- GEMM1: 256x256 tile, BK=64, 8 waves, 4-phase K-loop --------
// (unchanged from round 16)
__global__ __launch_bounds__(512, 2) void k_gemm1_256(
    const unsigned short* __restrict__ A, const unsigned short* __restrict__ Bt, int K,
    unsigned short* __restrict__ q, unsigned short* __restrict__ kk_,
    unsigned short* __restrict__ vT) {
    __shared__ unsigned short Ab[2][256 * 64];   // 32KB each
    __shared__ unsigned short Bb[2][256 * 64];
    const int tid = threadIdx.x;
    const int w = tid >> 6, l = tid & 63, g = l >> 4, lr = l & 15;
    const int wm = w >> 2, wn = w & 3;
    const int nwg = gridDim.x * gridDim.y, cpx = nwg >> 3;
    const int lin = blockIdx.y * gridDim.x + blockIdx.x;
    const int swz = (lin & 7) * cpx + (lin >> 3);
    const int m0 = (swz / gridDim.x) * 256, n0 = (swz % gridDim.x) * 256;
    f32x4 acc[8][4] = {};

    auto SPART = [&](int db, int kt, int i) {
        int ci = i * 512 + tid;
        int row = ci >> 3, pos = ci & 7;
        int gc = (pos ^ (row & 7)) * 8;
        gload16(A + (size_t)(m0 + row) * K + kt * 64 + gc, (char*)Ab[db] + ci * 16);
        gload16(Bt + (size_t)(n0 + row) * K + kt * 64 + gc, (char*)Bb[db] + ci * 16);
    };

#pragma unroll
    for (int i = 0; i < 4; i++) SPART(0, 0, i);
    asm volatile("s_waitcnt vmcnt(0)" ::: "memory");
    __builtin_amdgcn_s_barrier();
    __builtin_amdgcn_sched_barrier(0);

    const int nt = K >> 6;   // 16
    for (int t = 0; t < nt; ++t) {
        const int db = t & 1;
        const char* Ac = (const char*)Ab[db];
        const char* Bc = (const char*)Bb[db];
        bf16x8 bfv[4][2];
#pragma unroll
        for (int qp = 0; qp < 4; qp++) {
            if (qp == 0) {
#pragma unroll
                for (int ni = 0; ni < 4; ni++)
#pragma unroll
                    for (int kk = 0; kk < 2; kk++) {
                        int row = wn * 64 + ni * 16 + lr;
                        int c = kk * 4 + g;
                        bfv[ni][kk] = *(const bf16x8*)(Bc + row * 128 + ((c ^ (row & 7)) * 16));
                    }
            }
            bf16x8 af[2][2];
#pragma unroll
            for (int j = 0; j < 2; j++)
#pragma unroll
                for (int kk = 0; kk < 2; kk++) {
                    int row = wm * 128 + (2 * qp + j) * 16 + lr;
                    int c = kk * 4 + g;
                    af[j][kk] = *(const bf16x8*)(Ac + row * 128 + ((c ^ (row & 7)) * 16));
                }
            if (t < nt - 1 && qp < 2) {
                SPART(db ^ 1, t + 1, 2 * qp);
                SPART(db ^ 1, t + 1, 2 * qp + 1);
            }
            __builtin_amdgcn_s_barrier();
            asm volatile("s_waitcnt lgkmcnt(0)" ::: "memory");
            __builtin_amdgcn_sched_barrier(0);   // rule #18
            __builtin_amdgcn_s_setprio(1);
#pragma unroll
            for (int kk = 0; kk < 2; kk++)
#pragma unroll
                for (int j = 0; j < 2; j++)
#pragma unroll
                    for (int ni = 0; ni < 4; ni++)
                        acc[2 * qp + j][ni] = __builtin_amdgcn_mfma_f32_16x16x32_bf16(
                            af[j][kk], bfv[ni][kk], acc[2 * qp + j][ni], 0, 0, 0);
            __builtin_amdgcn_s_setprio(0);
            if (qp == 3 && t < nt - 1)
                asm volatile("s_waitcnt vmcnt(0)" ::: "memory");
            __builtin_amdgcn_s_barrier();
            __builtin_amdgcn_sched_barrier(0);
        }
    }

#pragma unroll
    for (int mi = 0; mi < 8; mi++) {
#pragma unroll
        for (int ni = 0; ni < 4; ni++) {
            int row0 = m0 + wm * 128 + mi * 16 + g * 4;
            int col = n0 + wn * 64 + ni * 16 + lr;
            int b = row0 >> 11, nn = row0 & 2047;
            int which = col >> 10, cc = col & 1023;
            int h = cc >> 6, d = cc & 63;
            if (which == 2) {
                u16x4 pv;
#pragma unroll
                for (int r = 0; r < 4; r++) pv[r] = f2bf(acc[mi][ni][r]);
                *(u16x4*)&vT[((size_t)(b * 16 + h) * 64 + d) * 2048 + nn] = pv;
            } else {
                unsigned short* dst = (which == 0) ? q : kk_;
                const float sc = (which == 0) ? QSCALE_LOG2E : 1.f;
#pragma unroll
                for (int r = 0; r < 4; r++)
                    dst[((size_t)(b * 16 + h) * 2048 + nn + r) * 64 + d] = f2bf(acc[mi][ni][r] * sc);
            }
        }
    }
}

// ---------------- GEMM (128x128, R12 dbuf): out-proj (MODE 3) ----------------
__global__ __launch_bounds__(256) void k_gemm3(
    const unsigned short* __restrict__ A, const unsigned short* __restrict__ Bt, int K,
    const float* __restrict__ bias, float* __restrict__ outf) {
    __shared__ unsigned short As[2][128 * 64];
    __shared__ unsigned short Bs[2][128 * 64];
    const int tid = threadIdx.x;
    const int w = tid >> 6, l = tid & 63, g = l >> 4, lr = l & 15;
    const int wr = w >> 1, wc = w & 1;
    const int nwg = gridDim.x * gridDim.y, cpx = nwg >> 3;
    const int lin = blockIdx.y * gridDim.x + blockIdx.x;
    const int swz = (lin & 7) * cpx + (lin >> 3);
    const int m0 = (swz / gridDim.x) * 128, n0 = (swz % gridDim.x) * 128;
    f32x4 acc[4][4] = {};

    auto STAGE = [&](int buf, int k0) {
#pragma unroll
        for (int i = 0; i < 4; i++) {
            int c = i * 256 + tid;
            gload16(A + (size_t)(m0 + (c >> 3)) * K + k0 + (c & 7) * 8, (char*)As[buf] + c * 16);
            gload16(Bt + (size_t)(n0 + (c >> 3)) * K + k0 + (c & 7) * 8, (char*)Bs[buf] + c * 16);
        }
    };

    STAGE(0, 0);
    asm volatile("s_waitcnt vmcnt(0)" ::: "memory");
    __builtin_amdgcn_s_barrier();
    __builtin_amdgcn_sched_barrier(0);

    int cur = 0;
    for (int k0 = 0; k0 < K; k0 += 64) {
        if (k0 + 64 < K) STAGE(cur ^ 1, k0 + 64);
        const unsigned short* Ac = As[cur];
        const unsigned short* Bc = Bs[cur];
#pragma unroll
        for (int kk = 0; kk < 2; kk++) {
            bf16x8 af[4], bfv[4];
#pragma unroll
            for (int mi = 0; mi < 4; mi++)
                af[mi] = *(const bf16x8*)(Ac + (wr * 64 + mi * 16 + lr) * 64 + kk * 32 + g * 8);
#pragma unroll
            for (int ni = 0; ni < 4; ni++)
                bfv[ni] = *(const bf16x8*)(Bc + (wc * 64 + ni * 16 + lr) * 64 + kk * 32 + g * 8);
#pragma unroll
            for (int mi = 0; mi < 4; mi++)
#pragma unroll
                for (int ni = 0; ni < 4; ni++)
                    acc[mi][ni] = __builtin_amdgcn_mfma_f32_16x16x32_bf16(af[mi], bfv[ni], acc[mi][ni], 0, 0, 0);
        }
        asm volatile("s_waitcnt vmcnt(0)" ::: "memory");
        __builtin_amdgcn_s_barrier();
        __builtin_amdgcn_sched_barrier(0);
        cur ^= 1;
    }

#pragma unroll
    for (int mi = 0; mi < 4; mi++)
#pragma unroll
        for (int ni = 0; ni < 4; ni++)
#pragma unroll
            for (int r = 0; r < 4; r++) {
                int row = m0 + wr * 64 + mi * 16 + g * 4 + r;
                int col = n0 + wc * 64 + ni * 16 + lr;
                outf[(size_t)row * 1024 + col] = acc[mi][ni][r] + bias[col];
            }
}

// ---------------- flash attention: R17 base + T15 intra-iter overlap ---------
// Round 19: revert R18; single bounded change on R17 (51.5us): reorder the
// per-iteration schedule from {QK01, SM0, SM1, PV01} to
// {QK01, SM0, PV0, SM1, PV1} -- PV0's 8 MFMAs (independent of SM1) issue and
// run UNDER SM1's exp2/pack VALU chain (T15 mechanism, m214-v36 +7-11%).
// V fragments are read once into regs in PV0 and reused in PV1 (+32 VGPR).
__global__ __launch_bounds__(512, 2) void k_attn(
    const unsigned short* __restrict__ qb, const unsigned short* __restrict__ kb,
    const unsigned short* __restrict__ vTb, unsigned short* __restrict__ ao) {
    __shared__ __align__(16) char smem[65536];   // [kvh][2 bufs][K 8KB | V 8KB]
    const int tid = threadIdx.x;
    const int w = tid >> 6, l = tid & 63, l31 = l & 31, hf = l >> 5;
    const int qg = w & 3, kvh = w >> 2;
    // XCD-grouped decode: 256 blocks = 8 xcd x (4 bh x 8 qb)
    const int bid = blockIdx.x;
    const int xcd = bid & 7, slot = bid >> 3;
    const int bh = xcd * 4 + (slot >> 3), qb_ = slot & 7;
    const int b = bh >> 4, h = bh & 15;
    const unsigned short* qp = qb + (size_t)bh * 131072;
    const unsigned short* kp = kb + (size_t)bh * 131072 + (size_t)kvh * 65536;
    const unsigned short* vTp = vTb + (size_t)bh * 131072 + kvh * 1024;

    const int qrow0 = qb_ * 256 + qg * 64 + l31;
    bf16x8 qf[2][4];
#pragma unroll
    for (int ti = 0; ti < 2; ti++)
#pragma unroll
        for (int dc = 0; dc < 4; dc++)
            qf[ti][dc] = *(const bf16x8*)(qp + (size_t)(qrow0 + ti * 32) * 64 + dc * 16 + hf * 8);

    f32x16 o_acc[2][2] = {};
    float l_r[2] = {0.f, 0.f};

    // reg-staging (R17): identical bytes/layout to the gload_lds path
    const int sr8 = l >> 3;
    const int sco = ((l & 7) ^ sr8) * 8;     // inverse-swizzled source chunk
    char* sbase = smem + kvh * 32768;

    u32x4 kreg[2], vreg[2];
    auto LOADR = [&](int kv0) {
#pragma unroll
        for (int i = 0; i < 2; i++) {
            int r = qg + 4 * i;
            kreg[i] = *(const u32x4*)(kp + (size_t)(kv0 + r * 8 + sr8) * 64 + sco);
            vreg[i] = *(const u32x4*)(vTp + (size_t)(r * 8 + sr8) * 2048 + kv0 + sco);
        }
    };
    auto WRITES = [&](char* dst) {
#pragma unroll
        for (int i = 0; i < 2; i++) {
            int r = qg + 4 * i;
            *(u32x4*)(dst + r * 1024 + (size_t)l * 16) = kreg[i];
            *(u32x4*)(dst + 8192 + r * 1024 + (size_t)l * 16) = vreg[i];
        }
    };

    // ---- prologue: tile 0 loaded, written, visible ----
    LOADR(0);
    asm volatile("s_waitcnt vmcnt(0)" ::: "memory");
    WRITES(sbase);
    asm volatile("s_waitcnt lgkmcnt(0)" ::: "memory");
    __builtin_amdgcn_s_barrier();
    __builtin_amdgcn_sched_barrier(0);

    const int lb = l31 & 7;
    int cur = 0;
    for (int t = 0; t < 16; ++t) {
        if (t < 15) LOADR((t + 1) * 64);   // issue early: flight = compute phase
        const char* p0 = sbase + cur * 16384;

        // ---- QK both tiles (each kf read feeds both) ----
        f32x16 s[2][2] = {};
        __builtin_amdgcn_s_setprio(1);
#pragma unroll
        for (int kt = 0; kt < 2; kt++)
#pragma unroll
            for (int dc = 0; dc < 4; dc++) {
                bf16x8 kf = *(const bf16x8*)(p0 + (kt * 32 + l31) * 128 + (((2 * dc + hf) ^ lb) * 16));
                s[0][kt] = __builtin_amdgcn_mfma_f32_32x32x16_bf16(kf, qf[0][dc], s[0][kt], 0, 0, 0);
                s[1][kt] = __builtin_amdgcn_mfma_f32_32x32x16_bf16(kf, qf[1][dc], s[1][kt], 0, 0, 0);
            }
        __builtin_amdgcn_s_setprio(0);

        // ---- SM0 -> pf0 ; PV0 (vf -> regs) ; SM1 -> pf1 ; PV1 (vf reuse) ----
        bf16x8 vfr[4][2];
        bf16x8 pf[2][4];
#pragma unroll
        for (int ti = 0; ti < 2; ti++) {
            float s0 = 0.f, s1 = 0.f, s2 = 0.f, s3 = 0.f;
#pragma unroll
            for (int kt = 0; kt < 2; kt++)
#pragma unroll
                for (int r = 0; r < 16; r += 4) {
                    float e0 = __builtin_amdgcn_exp2f(s[ti][kt][r]);
                    float e1 = __builtin_amdgcn_exp2f(s[ti][kt][r + 1]);
                    float e2 = __builtin_amdgcn_exp2f(s[ti][kt][r + 2]);
                    float e3 = __builtin_amdgcn_exp2f(s[ti][kt][r + 3]);
                    s[ti][kt][r] = e0; s[ti][kt][r + 1] = e1;
                    s[ti][kt][r + 2] = e2; s[ti][kt][r + 3] = e3;
                    s0 += e0; s1 += e1; s2 += e2; s3 += e3;
                }
            float ssum = (s0 + s1) + (s2 + s3);
            ssum += __shfl_xor(ssum, 32);
            l_r[ti] += ssum;
#pragma unroll
            for (int kt = 0; kt < 2; kt++) {
                unsigned wd[8];
#pragma unroll
                for (int i = 0; i < 8; i++)
                    wd[i] = pack2bf(s[ti][kt][2 * i], s[ti][kt][2 * i + 1]);
#pragma unroll
                for (int cl = 0; cl < 2; cl++) {
                    unsigned b0 = wd[4 * cl + 0], b2 = wd[4 * cl + 2];
                    unsigned b1 = wd[4 * cl + 1], b3 = wd[4 * cl + 3];
                    pswap(b0, b2);
                    pswap(b1, b3);
                    u32x4 bw; bw[0] = b0; bw[1] = b1; bw[2] = b2; bw[3] = b3;
                    pf[ti][2 * kt + cl] = __builtin_bit_cast(bf16x8, bw);
                }
            }
            // PV for THIS tile immediately: its MFMAs run under the other
            // tile's softmax VALU (T15 overlap). vf loaded to regs on ti=0.
            __builtin_amdgcn_s_setprio(1);
#pragma unroll
            for (int c4 = 0; c4 < 4; c4++)
#pragma unroll
                for (int dt = 0; dt < 2; dt++) {
                    if (ti == 0)
                        vfr[c4][dt] = *(const bf16x8*)(p0 + 8192 + (dt * 32 + l31) * 128 + (((2 * c4 + hf) ^ lb) * 16));
                    o_acc[ti][dt] = __builtin_amdgcn_mfma_f32_32x32x16_bf16(vfr[c4][dt], pf[ti][c4], o_acc[ti][dt], 0, 0, 0);
                }
            __builtin_amdgcn_s_setprio(0);
        }

        // ---- T14 write-late: regs arrived under compute; write next buf ----
        if (t < 15) {
            asm volatile("s_waitcnt vmcnt(0)" ::: "memory");
            WRITES(sbase + (cur ^ 1) * 16384);
            asm volatile("s_waitcnt lgkmcnt(0)" ::: "memory");
            __builtin_amdgcn_s_barrier();
            __builtin_amdgcn_sched_barrier(0);
        }
        cur ^= 1;
    }

    // ---- merge the two KV halves, two passes (one per q-tile) ----
    float* dO = (float*)(smem + qg * 8448);            // [64 lane][33] padded
    float* dL = (float*)(smem + 33792 + qg * 256);
#pragma unroll
    for (int ti = 0; ti < 2; ti++) {
        __syncthreads();
        if (kvh == 1) {
#pragma unroll
            for (int i = 0; i < 16; i++) dO[l * 33 + i] = o_acc[ti][0][i];
#pragma unroll
            for (int i = 0; i < 16; i++) dO[l * 33 + 16 + i] = o_acc[ti][1][i];
            dL[l] = l_r[ti];
        }
        __syncthreads();
        if (kvh == 0) {
            float linv = 1.f / (l_r[ti] + dL[l]);
            unsigned short* aop = ao + ((size_t)b * 2048 + qrow0 + ti * 32) * 1024 + h * 64;
#pragma unroll
            for (int dt = 0; dt < 2; dt++)
#pragma unroll
                for (int rg = 0; rg < 4; rg++) {
                    u16x4 pv;
#pragma unroll
                    for (int k = 0; k < 4; k++) {
                        int r = rg * 4 + k;
                        pv[k] = f2bf((o_acc[ti][dt][r] + dO[l * 33 + dt * 16 + r]) * linv);
                    }
                    *(u16x4*)(aop + 8 * rg + 4 * hf + 32 * dt) = pv;
                }
        }
    }
}

extern "C" void kernel_launch(void* const* d_in, const int* in_sizes, int n_in,
                              void* d_out, int out_size, void* d_ws, size_t ws_size,
                              hipStream_t stream) {
    (void)in_sizes; (void)n_in; (void)out_size; (void)ws_size;
    const float* x      = (const float*)d_in[0];
    const float* w_qkv  = (const float*)d_in[1];
    const float* w_proj = (const float*)d_in[2];
    const float* b_proj = (const float*)d_in[3];
    float* out = (float*)d_out;
    char* ws = (char*)d_ws;

    // workspace layout (bytes); ao aliases xb (xb dead after GEMM1)
    unsigned short* xb     = (unsigned short*)(ws);             // [4096][1024] bf16
    unsigned short* ao     = (unsigned short*)(ws);             // [4096][1024] bf16 (alias)
    unsigned short* wqkvT  = (unsigned short*)(ws + 8388608);   // [3072][1024] bf16
    unsigned short* wprojT = (unsigned short*)(ws + 14680064);  // [1024][1024] bf16
    unsigned short* qb     = (unsigned short*)(ws + 16777216);  // [2][16][2048][64] bf16
    unsigned short* kb     = (unsigned short*)(ws + 25165824);  // [2][16][2048][64] bf16
    unsigned short* vTb    = (unsigned short*)(ws + 33554432);  // [2][16][64][2048] bf16

    k_cvt<<<2048, 256, 0, stream>>>(x, xb, 1048576);
    k_transpose<<<dim3(48, 16), 256, 0, stream>>>(w_qkv, wqkvT, 3072);
    k_transpose<<<dim3(16, 16), 256, 0, stream>>>(w_proj, wprojT, 1024);
    k_gemm1_256<<<dim3(12, 16), 512, 0, stream>>>(xb, wqkvT, 1024, qb, kb, vTb);
    k_attn<<<256, 512, 0, stream>>>(qb, kb, vTb, ao);
    k_gemm3<<<dim3(8, 32), 256, 0, stream>>>(ao, wprojT, 1024, b_proj, out);
}

// Round 20
// 111.934 us; speedup vs baseline: 1.1119x; 1.0434x over previous
//
#include <hip/hip_runtime.h>
#include <stdint.h>

typedef float f32x4 __attribute__((ext_vector_type(4)));
typedef float f32x16 __attribute__((ext_vector_type(16)));
typedef __bf16 bf16x8 __attribute__((ext_vector_type(8)));
typedef unsigned int u32x4 __attribute__((ext_vector_type(4)));
typedef unsigned short u16x4 __attribute__((ext_vector_type(4)));

#define DEV __device__ __forceinline__

// SCALE * log2(e): softmax computed base-2 (exact-equivalent)
#define QSCALE_LOG2E 0.18033688011112042f

// round-to-nearest-even f32 -> bf16 bits
DEV unsigned short f2bf(float f) {
    unsigned u = __builtin_bit_cast(unsigned, f);
    u += 0x7fffu + ((u >> 16) & 1u);
    return (unsigned short)(u >> 16);
}

// native cast path: compiler emits v_cvt_pk_bf16_f32 for pairs (RNE)
DEV unsigned pack2bf(float a, float b) {
    unsigned short ua = __builtin_bit_cast(unsigned short, (__bf16)a);
    unsigned short ub = __builtin_bit_cast(unsigned short, (__bf16)b);
    return (unsigned)ua | ((unsigned)ub << 16);
}

// lane i <-> lane i^32 pairwise exchange of two registers (gfx950)
DEV void pswap(unsigned& a, unsigned& b) {
    asm volatile("v_permlane32_swap_b32 %0, %1" : "+v"(a), "+v"(b));
}

// async global->LDS, 16B per lane. LDS dst must be wave-uniform-base + lane*16.
DEV void gload16(const void* g, void* l) {
    __builtin_amdgcn_global_load_lds(
        (const __attribute__((address_space(1))) unsigned int*)(uintptr_t)g,
        (__attribute__((address_space(3))) unsigned int*)(unsigned int)(uintptr_t)l,
        16, 0, 0);
}

// ---------------- fused prep: cvt x + transpose w_qkv + transpose w_proj -----
// Round 20: one launch instead of three (removes two launch/drain gaps).
// blocks [0,2048): x fp32 -> bf16; [2048,2816): w_qkv [1024][3072] -> T;
// [2816,3072): w_proj [1024][1024] -> T. Whole blocks per path.
__global__ __launch_bounds__(256) void k_prep(
    const float* __restrict__ x, unsigned short* __restrict__ xb,
    const float* __restrict__ w_qkv, unsigned short* __restrict__ wqkvT,
    const float* __restrict__ w_proj, unsigned short* __restrict__ wprojT) {
    __shared__ unsigned short tl[64][68];
    const int bid = blockIdx.x;
    if (bid < 2048) {
        int i = bid * 256 + threadIdx.x;
        const int st = 2048 * 256;
        for (; i < 1048576; i += st) {
            f32x4 v = *(const f32x4*)(x + (size_t)i * 4);
            u16x4 o;
            o[0] = f2bf(v[0]); o[1] = f2bf(v[1]); o[2] = f2bf(v[2]); o[3] = f2bf(v[3]);
            *(u16x4*)(xb + (size_t)i * 4) = o;
        }
        return;
    }
    const float* in;
    unsigned short* out;
    int Nc, n0, k0;
    if (bid < 2816) {
        int tq = bid - 2048;
        in = w_qkv; out = wqkvT; Nc = 3072;
        n0 = (tq % 48) * 64; k0 = (tq / 48) * 64;
    } else {
        int tp = bid - 2816;
        in = w_proj; out = wprojT; Nc = 1024;
        n0 = (tp & 15) * 64; k0 = (tp >> 4) * 64;
    }
#pragma unroll
    for (int i = 0; i < 16; i++) {
        int idx = i * 256 + threadIdx.x;
        int kr = idx >> 6, nc = idx & 63;
        tl[kr][nc] = f2bf(in[(size_t)(k0 + kr) * Nc + n0 + nc]);
    }
    __syncthreads();
#pragma unroll
    for (int i = 0; i < 8; i++) {
        int idx = i * 256 + threadIdx.x;
        int nr = idx >> 5, kp2 = idx & 31;
        unsigned vv = (unsigned)tl[kp2 * 2][nr] | ((unsigned)tl[kp2 * 2 + 1][nr] << 16);
        *(unsigned*)(out + (size_t)(n0 + nr) * 1024 + k0 + kp2 * 2) = vv;
    }
}

// ---------------- GEMM1: 256x256 tile, BK=64, 8 waves, 4-phase K-loop --------
// (unchanged from round 16)
__global__ __launch_bounds__(512, 2) void k_gemm1_256(
    const unsigned short* __restrict__ A, const unsigned short* __restrict__ Bt, int K,
    unsigned short* __restrict__ q, unsigned short* __restrict__ kk_,
    unsigned short* __restrict__ vT) {
    __shared__ unsigned short Ab[2][256 * 64];   // 32KB each
    __shared__ unsigned short Bb[2][256 * 64];
    const int tid = threadIdx.x;
    const int w = tid >> 6, l = tid & 63, g = l >> 4, lr = l & 15;
    const int wm = w >> 2, wn = w & 3;
    const int nwg = gridDim.x * gridDim.y, cpx = nwg >> 3;
    const int lin = blockIdx.y * gridDim.x + blockIdx.x;
    const int swz = (lin & 7) * cpx + (lin >> 3);
    const int m0 = (swz / gridDim.x) * 256, n0 = (swz % gridDim.x) * 256;
    f32x4 acc[8][4] = {};

    auto SPART = [&](int db, int kt, int i) {
        int ci = i * 512 + tid;
        int row = ci >> 3, pos = ci & 7;
        int gc = (pos ^ (row & 7)) * 8;
        gload16(A + (size_t)(m0 + row) * K + kt * 64 + gc, (char*)Ab[db] + ci * 16);
        gload16(Bt + (size_t)(n0 + row) * K + kt * 64 + gc, (char*)Bb[db] + ci * 16);
    };

#pragma unroll
    for (int i = 0; i < 4; i++) SPART(0, 0, i);
    asm volatile("s_waitcnt vmcnt(0)" ::: "memory");
    __builtin_amdgcn_s_barrier();
    __builtin_amdgcn_sched_barrier(0);

    const int nt = K >> 6;   // 16
    for (int t = 0; t < nt; ++t) {
        const int db = t & 1;
        const char* Ac = (const char*)Ab[db];
        const char* Bc = (const char*)Bb[db];
        bf16x8 bfv[4][2];
#pragma unroll
        for (int qp = 0; qp < 4; qp++) {
            if (qp == 0) {
#pragma unroll
                for (int ni = 0; ni < 4; ni++)
#pragma unroll
                    for (int kk = 0; kk < 2; kk++) {
                        int row = wn * 64 + ni * 16 + lr;
                        int c = kk * 4 + g;
                        bfv[ni][kk] = *(const bf16x8*)(Bc + row * 128 + ((c ^ (row & 7)) * 16));
                    }
            }
            bf16x8 af[2][2];
#pragma unroll
            for (int j = 0; j < 2; j++)
#pragma unroll
                for (int kk = 0; kk < 2; kk++) {
                    int row = wm * 128 + (2 * qp + j) * 16 + lr;
                    int c = kk * 4 + g;
                    af[j][kk] = *(const bf16x8*)(Ac + row * 128 + ((c ^ (row & 7)) * 16));
                }
            if (t < nt - 1 && qp < 2) {
                SPART(db ^ 1, t + 1, 2 * qp);
                SPART(db ^ 1, t + 1, 2 * qp + 1);
            }
            __builtin_amdgcn_s_barrier();
            asm volatile("s_waitcnt lgkmcnt(0)" ::: "memory");
            __builtin_amdgcn_sched_barrier(0);   // rule #18
            __builtin_amdgcn_s_setprio(1);
#pragma unroll
            for (int kk = 0; kk < 2; kk++)
#pragma unroll
                for (int j = 0; j < 2; j++)
#pragma unroll
                    for (int ni = 0; ni < 4; ni++)
                        acc[2 * qp + j][ni] = __builtin_amdgcn_mfma_f32_16x16x32_bf16(
                            af[j][kk], bfv[ni][kk], acc[2 * qp + j][ni], 0, 0, 0);
            __builtin_amdgcn_s_setprio(0);
            if (qp == 3 && t < nt - 1)
                asm volatile("s_waitcnt vmcnt(0)" ::: "memory");
            __builtin_amdgcn_s_barrier();
            __builtin_amdgcn_sched_barrier(0);
        }
    }

#pragma unroll
    for (int mi = 0; mi < 8; mi++) {
#pragma unroll
        for (int ni = 0; ni < 4; ni++) {
            int row0 = m0 + wm * 128 + mi * 16 + g * 4;
            int col = n0 + wn * 64 + ni * 16 + lr;
            int b = row0 >> 11, nn = row0 & 2047;
            int which = col >> 10, cc = col & 1023;
            int h = cc >> 6, d = cc & 63;
            if (which == 2) {
                u16x4 pv;
#pragma unroll
                for (int r = 0; r < 4; r++) pv[r] = f2bf(acc[mi][ni][r]);
                *(u16x4*)&vT[((size_t)(b * 16 + h) * 64 + d) * 2048 + nn] = pv;
            } else {
                unsigned short* dst = (which == 0) ? q : kk_;
                const float sc = (which == 0) ? QSCALE_LOG2E : 1.f;
#pragma unroll
                for (int r = 0; r < 4; r++)
                    dst[((size_t)(b * 16 + h) * 2048 + nn + r) * 64 + d] = f2bf(acc[mi][ni][r] * sc);
            }
        }
    }
}

// ---------------- GEMM (128x128, R12 dbuf): out-proj (MODE 3) ----------------
__global__ __launch_bounds__(256) void k_gemm3(
    const unsigned short* __restrict__ A, const unsigned short* __restrict__ Bt, int K,
    const float* __restrict__ bias, float* __restrict__ outf) {
    __shared__ unsigned short As[2][128 * 64];
    __shared__ unsigned short Bs[2][128 * 64];
    const int tid = threadIdx.x;
    const int w = tid >> 6, l = tid & 63, g = l >> 4, lr = l & 15;
    const int wr = w >> 1, wc = w & 1;
    const int nwg = gridDim.x * gridDim.y, cpx = nwg >> 3;
    const int lin = blockIdx.y * gridDim.x + blockIdx.x;
    const int swz = (lin & 7) * cpx + (lin >> 3);
    const int m0 = (swz / gridDim.x) * 128, n0 = (swz % gridDim.x) * 128;
    f32x4 acc[4][4] = {};

    auto STAGE = [&](int buf, int k0) {
#pragma unroll
        for (int i = 0; i < 4; i++) {
            int c = i * 256 + tid;
            gload16(A + (size_t)(m0 + (c >> 3)) * K + k0 + (c & 7) * 8, (char*)As[buf] + c * 16);
            gload16(Bt + (size_t)(n0 + (c >> 3)) * K + k0 + (c & 7) * 8, (char*)Bs[buf] + c * 16);
        }
    };

    STAGE(0, 0);
    asm volatile("s_waitcnt vmcnt(0)" ::: "memory");
    __builtin_amdgcn_s_barrier();
    __builtin_amdgcn_sched_barrier(0);

    int cur = 0;
    for (int k0 = 0; k0 < K; k0 += 64) {
        if (k0 + 64 < K) STAGE(cur ^ 1, k0 + 64);
        const unsigned short* Ac = As[cur];
        const unsigned short* Bc = Bs[cur];
#pragma unroll
        for (int kk = 0; kk < 2; kk++) {
            bf16x8 af[4], bfv[4];
#pragma unroll
            for (int mi = 0; mi < 4; mi++)
                af[mi] = *(const bf16x8*)(Ac + (wr * 64 + mi * 16 + lr) * 64 + kk * 32 + g * 8);
#pragma unroll
            for (int ni = 0; ni < 4; ni++)
                bfv[ni] = *(const bf16x8*)(Bc + (wc * 64 + ni * 16 + lr) * 64 + kk * 32 + g * 8);
#pragma unroll
            for (int mi = 0; mi < 4; mi++)
#pragma unroll
                for (int ni = 0; ni < 4; ni++)
                    acc[mi][ni] = __builtin_amdgcn_mfma_f32_16x16x32_bf16(af[mi], bfv[ni], acc[mi][ni], 0, 0, 0);
        }
        asm volatile("s_waitcnt vmcnt(0)" ::: "memory");
        __builtin_amdgcn_s_barrier();
        __builtin_amdgcn_sched_barrier(0);
        cur ^= 1;
    }

#pragma unroll
    for (int mi = 0; mi < 4; mi++)
#pragma unroll
        for (int ni = 0; ni < 4; ni++)
#pragma unroll
            for (int r = 0; r < 4; r++) {
                int row = m0 + wr * 64 + mi * 16 + g * 4 + r;
                int col = n0 + wc * 64 + ni * 16 + lr;
                outf[(size_t)row * 1024 + col] = acc[mi][ni][r] + bias[col];
            }
}

// ---------------- flash attention: dual q-tile, REG-STAGED (R17, best 51.5us) -
__global__ __launch_bounds__(512, 2) void k_attn(
    const unsigned short* __restrict__ qb, const unsigned short* __restrict__ kb,
    const unsigned short* __restrict__ vTb, unsigned short* __restrict__ ao) {
    __shared__ __align__(16) char smem[65536];   // [kvh][2 bufs][K 8KB | V 8KB]
    const int tid = threadIdx.x;
    const int w = tid >> 6, l = tid & 63, l31 = l & 31, hf = l >> 5;
    const int qg = w & 3, kvh = w >> 2;
    // XCD-grouped decode: 256 blocks = 8 xcd x (4 bh x 8 qb)
    const int bid = blockIdx.x;
    const int xcd = bid & 7, slot = bid >> 3;
    const int bh = xcd * 4 + (slot >> 3), qb_ = slot & 7;
    const int b = bh >> 4, h = bh & 15;
    const unsigned short* qp = qb + (size_t)bh * 131072;
    const unsigned short* kp = kb + (size_t)bh * 131072 + (size_t)kvh * 65536;
    const unsigned short* vTp = vTb + (size_t)bh * 131072 + kvh * 1024;

    const int qrow0 = qb_ * 256 + qg * 64 + l31;
    bf16x8 qf[2][4];
#pragma unroll
    for (int ti = 0; ti < 2; ti++)
#pragma unroll
        for (int dc = 0; dc < 4; dc++)
            qf[ti][dc] = *(const bf16x8*)(qp + (size_t)(qrow0 + ti * 32) * 64 + dc * 16 + hf * 8);

    f32x16 o_acc[2][2] = {};
    float l_r[2] = {0.f, 0.f};

    // reg-staging: identical bytes/layout to the gload_lds path
    const int sr8 = l >> 3;
    const int sco = ((l & 7) ^ sr8) * 8;     // inverse-swizzled source chunk
    char* sbase = smem + kvh * 32768;

    u32x4 kreg[2], vreg[2];
    auto LOADR = [&](int kv0) {
#pragma unroll
        for (int i = 0; i < 2; i++) {
            int r = qg + 4 * i;
            kreg[i] = *(const u32x4*)(kp + (size_t)(kv0 + r * 8 + sr8) * 64 + sco);
            vreg[i] = *(const u32x4*)(vTp + (size_t)(r * 8 + sr8) * 2048 + kv0 + sco);
        }
    };
    auto WRITES = [&](char* dst) {
#pragma unroll
        for (int i = 0; i < 2; i++) {
            int r = qg + 4 * i;
            *(u32x4*)(dst + r * 1024 + (size_t)l * 16) = kreg[i];
            *(u32x4*)(dst + 8192 + r * 1024 + (size_t)l * 16) = vreg[i];
        }
    };

    // ---- prologue: tile 0 loaded, written, visible ----
    LOADR(0);
    asm volatile("s_waitcnt vmcnt(0)" ::: "memory");
    WRITES(sbase);
    asm volatile("s_waitcnt lgkmcnt(0)" ::: "memory");
    __builtin_amdgcn_s_barrier();
    __builtin_amdgcn_sched_barrier(0);

    const int lb = l31 & 7;
    int cur = 0;
    for (int t = 0; t < 16; ++t) {
        if (t < 15) LOADR((t + 1) * 64);   // issue early: flight = compute phase
        const char* p0 = sbase + cur * 16384;

        // ---- S^T = K x Q : each kf read feeds BOTH q-tiles ----
        f32x16 s[2][2] = {};
        __builtin_amdgcn_s_setprio(1);
#pragma unroll
        for (int kt = 0; kt < 2; kt++)
#pragma unroll
            for (int dc = 0; dc < 4; dc++) {
                bf16x8 kf = *(const bf16x8*)(p0 + (kt * 32 + l31) * 128 + (((2 * dc + hf) ^ lb) * 16));
                s[0][kt] = __builtin_amdgcn_mfma_f32_32x32x16_bf16(kf, qf[0][dc], s[0][kt], 0, 0, 0);
                s[1][kt] = __builtin_amdgcn_mfma_f32_32x32x16_bf16(kf, qf[1][dc], s[1][kt], 0, 0, 0);
            }
        __builtin_amdgcn_s_setprio(0);

        // ---- softmax numerator per tile: P = exp2(s), no max subtraction ----
        bf16x8 pf[2][4];
#pragma unroll
        for (int ti = 0; ti < 2; ti++) {
            float s0 = 0.f, s1 = 0.f, s2 = 0.f, s3 = 0.f;
#pragma unroll
            for (int kt = 0; kt < 2; kt++)
#pragma unroll
                for (int r = 0; r < 16; r += 4) {
                    float e0 = __builtin_amdgcn_exp2f(s[ti][kt][r]);
                    float e1 = __builtin_amdgcn_exp2f(s[ti][kt][r + 1]);
                    float e2 = __builtin_amdgcn_exp2f(s[ti][kt][r + 2]);
                    float e3 = __builtin_amdgcn_exp2f(s[ti][kt][r + 3]);
                    s[ti][kt][r] = e0; s[ti][kt][r + 1] = e1;
                    s[ti][kt][r + 2] = e2; s[ti][kt][r + 3] = e3;
                    s0 += e0; s1 += e1; s2 += e2; s3 += e3;
                }
            float ssum = (s0 + s1) + (s2 + s3);
            ssum += __shfl_xor(ssum, 32);
            l_r[ti] += ssum;
#pragma unroll
            for (int kt = 0; kt < 2; kt++) {
                unsigned wd[8];
#pragma unroll
                for (int i = 0; i < 8; i++)
                    wd[i] = pack2bf(s[ti][kt][2 * i], s[ti][kt][2 * i + 1]);
#pragma unroll
                for (int cl = 0; cl < 2; cl++) {
                    unsigned b0 = wd[4 * cl + 0], b2 = wd[4 * cl + 2];
                    unsigned b1 = wd[4 * cl + 1], b3 = wd[4 * cl + 3];
                    pswap(b0, b2);
                    pswap(b1, b3);
                    u32x4 bw; bw[0] = b0; bw[1] = b1; bw[2] = b2; bw[3] = b3;
                    pf[ti][2 * kt + cl] = __builtin_bit_cast(bf16x8, bw);
                }
            }
        }

        // ---- O^T += V^T x P : each vf read feeds BOTH q-tiles ----
        __builtin_amdgcn_s_setprio(1);
#pragma unroll
        for (int c4 = 0; c4 < 4; c4++)
#pragma unroll
            for (int dt = 0; dt < 2; dt++) {
                bf16x8 vf = *(const bf16x8*)(p0 + 8192 + (dt * 32 + l31) * 128 + (((2 * c4 + hf) ^ lb) * 16));
                o_acc[0][dt] = __builtin_amdgcn_mfma_f32_32x32x16_bf16(vf, pf[0][c4], o_acc[0][dt], 0, 0, 0);
                o_acc[1][dt] = __builtin_amdgcn_mfma_f32_32x32x16_bf16(vf, pf[1][c4], o_acc[1][dt], 0, 0, 0);
            }
        __builtin_amdgcn_s_setprio(0);

        // ---- T14 write-late: regs arrived under compute; write next buf ----
        if (t < 15) {
            asm volatile("s_waitcnt vmcnt(0)" ::: "memory");
            WRITES(sbase + (cur ^ 1) * 16384);
            asm volatile("s_waitcnt lgkmcnt(0)" ::: "memory");
            __builtin_amdgcn_s_barrier();
            __builtin_amdgcn_sched_barrier(0);
        }
        cur ^= 1;
    }

    // ---- merge the two KV halves, two passes (one per q-tile) ----
    float* dO = (float*)(smem + qg * 8448);            // [64 lane][33] padded
    float* dL = (float*)(smem + 33792 + qg * 256);
#pragma unroll
    for (int ti = 0; ti < 2; ti++) {
        __syncthreads();
        if (kvh == 1) {
#pragma unroll
            for (int i = 0; i < 16; i++) dO[l * 33 + i] = o_acc[ti][0][i];
#pragma unroll
            for (int i = 0; i < 16; i++) dO[l * 33 + 16 + i] = o_acc[ti][1][i];
            dL[l] = l_r[ti];
        }
        __syncthreads();
        if (kvh == 0) {
            float linv = 1.f / (l_r[ti] + dL[l]);
            unsigned short* aop = ao + ((size_t)b * 2048 + qrow0 + ti * 32) * 1024 + h * 64;
#pragma unroll
            for (int dt = 0; dt < 2; dt++)
#pragma unroll
                for (int rg = 0; rg < 4; rg++) {
                    u16x4 pv;
#pragma unroll
                    for (int k = 0; k < 4; k++) {
                        int r = rg * 4 + k;
                        pv[k] = f2bf((o_acc[ti][dt][r] + dO[l * 33 + dt * 16 + r]) * linv);
                    }
                    *(u16x4*)(aop + 8 * rg + 4 * hf + 32 * dt) = pv;
                }
        }
    }
}

extern "C" void kernel_launch(void* const* d_in, const int* in_sizes, int n_in,
                              void* d_out, int out_size, void* d_ws, size_t ws_size,
                              hipStream_t stream) {
    (void)in_sizes; (void)n_in; (void)out_size; (void)ws_size;
    const float* x      = (const float*)d_in[0];
    const float* w_qkv  = (const float*)d_in[1];
    const float* w_proj = (const float*)d_in[2];
    const float* b_proj = (const float*)d_in[3];
    float* out = (float*)d_out;
    char* ws = (char*)d_ws;

    // workspace layout (bytes); ao aliases xb (xb dead after GEMM1)
    unsigned short* xb     = (unsigned short*)(ws);             // [4096][1024] bf16
    unsigned short* ao     = (unsigned short*)(ws);             // [4096][1024] bf16 (alias)
    unsigned short* wqkvT  = (unsigned short*)(ws + 8388608);   // [3072][1024] bf16
    unsigned short* wprojT = (unsigned short*)(ws + 14680064);  // [1024][1024] bf16
    unsigned short* qb     = (unsigned short*)(ws + 16777216);  // [2][16][2048][64] bf16
    unsigned short* kb     = (unsigned short*)(ws + 25165824);  // [2][16][2048][64] bf16
    unsigned short* vTb    = (unsigned short*)(ws + 33554432);  // [2][16][64][2048] bf16

    k_prep<<<3072, 256, 0, stream>>>(x, xb, w_qkv, wqkvT, w_proj, wprojT);
    k_gemm1_256<<<dim3(12, 16), 512, 0, stream>>>(xb, wqkvT, 1024, qb, kb, vTb);
    k_attn<<<256, 512, 0, stream>>>(qb, kb, vTb, ao);
    k_gemm3<<<dim3(8, 32), 256, 0, stream>>>(ao, wprojT, 1024, b_proj, out);
}